// Round 1
// baseline (1649.629 us; speedup 1.0000x reference)
//
#include <hip/hip_runtime.h>
#include <cstdint>

// Problem constants (dims hard-coded; N/E derived from in_sizes at launch)
#define HD    128
#define OUTD  10
#define NG    512
#define KSTEPS 10

// ---------------------------------------------------------------------------
// 1) Collapse the two linear layers: Wc = W1@W2, bc = b1@W2 + b2
// ---------------------------------------------------------------------------
__global__ void wc_kernel(const float* __restrict__ W1, const float* __restrict__ b1,
                          const float* __restrict__ W2, const float* __restrict__ b2,
                          float* __restrict__ Wc, float* __restrict__ bc) {
    int idx = blockIdx.x * 256 + threadIdx.x;      // 0..16383
    int d = idx >> 7, j = idx & 127;
    float s = 0.f;
    for (int t = 0; t < HD; t++) s += W1[d * HD + t] * W2[t * HD + j];
    Wc[idx] = s;
    if (idx < HD) {
        float sb = b2[idx];
        for (int t = 0; t < HD; t++) sb += b1[t] * W2[t * HD + idx];
        bc[idx] = sb;
    }
}

// ---------------------------------------------------------------------------
// 2) h[n][j] = sum_d feat[d][n] * Wc[d][j] + bc[j]   (features are [HD, N])
//    Block: 256 threads = 128 j x 2 halves; 16 nodes per block; 8 acc/thread.
// ---------------------------------------------------------------------------
__global__ void __launch_bounds__(256) feat_kernel(
        const float* __restrict__ feat, const float* __restrict__ Wc,
        const float* __restrict__ bc, float* __restrict__ h, int N) {
    __shared__ float ftile[HD][16];
    int tid = threadIdx.x;
    int n0 = blockIdx.x * 16;
    // stage feature tile: 2048 elems, 8 per thread
    #pragma unroll
    for (int r = 0; r < 8; r++) {
        int l = tid * 8 + r;
        int d = l >> 4, n = l & 15;
        int nn = n0 + n;
        ftile[d][n] = (nn < N) ? feat[(size_t)d * N + nn] : 0.f;
    }
    __syncthreads();
    int j = tid & 127, half = tid >> 7;
    float acc[8];
    #pragma unroll
    for (int i = 0; i < 8; i++) acc[i] = 0.f;
    for (int d = 0; d < HD; d++) {
        float w = Wc[d * HD + j];
        #pragma unroll
        for (int i = 0; i < 8; i++) acc[i] += ftile[d][half * 8 + i] * w;
    }
    float bb = bc[j];
    #pragma unroll
    for (int i = 0; i < 8; i++) {
        int n = n0 + half * 8 + i;
        if (n < N) h[(size_t)n * HD + j] = acc[i] + bb;
    }
}

// ---------------------------------------------------------------------------
// 3) CSR build (dst-sorted edge lists): count -> scan -> scatter
// ---------------------------------------------------------------------------
__global__ void count_kernel(const int* __restrict__ ei, int* __restrict__ cnt, int E) {
    int e = blockIdx.x * 256 + threadIdx.x;
    if (e < E) atomicAdd(&cnt[ei[E + e]], 1);       // dst row of edge_index
}

// Single block of 1024 threads: exclusive prefix over N counts.
// cnt is read as counts and overwritten with row starts (becomes the cursor).
__global__ void scan_kernel(int* __restrict__ cnt, int* __restrict__ row_ptr,
                            int N, int E) {
    __shared__ int part[1024];
    int t = threadIdx.x;
    int chunk = (N + 1023) / 1024;
    int lo = t * chunk, hi = min(lo + chunk, N);
    int s = 0;
    for (int i = lo; i < hi; i++) s += cnt[i];
    part[t] = s;
    __syncthreads();
    for (int off = 1; off < 1024; off <<= 1) {      // inclusive Hillis-Steele
        int v = (t >= off) ? part[t - off] : 0;
        __syncthreads();
        part[t] += v;
        __syncthreads();
    }
    int run = (t == 0) ? 0 : part[t - 1];           // exclusive for this chunk
    for (int i = lo; i < hi; i++) {
        int c = cnt[i];
        row_ptr[i] = run;
        cnt[i] = run;                                // cursor init
        run += c;
    }
    if (t == 1023) row_ptr[N] = E;
}

__global__ void scatter_kernel(const int* __restrict__ ei, const float* __restrict__ ew_in,
                               int* __restrict__ cursor, int* __restrict__ es,
                               float* __restrict__ ew, int E) {
    int e = blockIdx.x * 256 + threadIdx.x;
    if (e < E) {
        int d = ei[E + e];
        int p = atomicAdd(&cursor[d], 1);
        es[p] = ei[e];
        ew[p] = ew_in[e];
    }
}

// ---------------------------------------------------------------------------
// 4) One APPNP step: x_dst[n] = 0.9 * sum_{e in csr[n]} w_e * x_src[src_e] + 0.1 * h[n]
//    One wave per dst node; lane holds dims [2*lane, 2*lane+1].
// ---------------------------------------------------------------------------
__global__ void __launch_bounds__(256) prop_kernel(
        const float* __restrict__ xs, float* __restrict__ xd,
        const float* __restrict__ h, const int* __restrict__ row_ptr,
        const int* __restrict__ es, const float* __restrict__ ew, int N) {
    int wid = threadIdx.x >> 6, lane = threadIdx.x & 63;
    int node = blockIdx.x * 4 + wid;
    if (node >= N) return;
    int rs = row_ptr[node], re = row_ptr[node + 1];
    float ax = 0.f, ay = 0.f;
    for (int base = rs; base < re; base += 64) {
        int e = base + lane;
        int sidx = 0; float wv = 0.f;
        if (e < re) { sidx = es[e]; wv = ew[e]; }
        int cnt = min(64, re - base);
        for (int k = 0; k < cnt; k++) {
            int ss = __shfl(sidx, k);
            float ww = __shfl(wv, k);
            const float2 v = *(const float2*)(xs + (size_t)ss * HD + lane * 2);
            ax += ww * v.x;
            ay += ww * v.y;
        }
    }
    const float2 hv = *(const float2*)(h + (size_t)node * HD + lane * 2);
    float2 o;
    o.x = 0.9f * ax + 0.1f * hv.x;
    o.y = 0.9f * ay + 0.1f * hv.y;
    *(float2*)(xd + (size_t)node * HD + lane * 2) = o;
}

// ---------------------------------------------------------------------------
// 5) Pool: batch is sorted -> running accumulator, atomic only on boundary.
//    128 threads = j dims; POOL_CHUNK nodes per block.
// ---------------------------------------------------------------------------
#define POOL_CHUNK 128
__global__ void pool_kernel(const float* __restrict__ x, const int* __restrict__ batch,
                            float* __restrict__ pooled, int N) {
    int j = threadIdx.x;
    int n0 = blockIdx.x * POOL_CHUNK;
    if (n0 >= N) return;
    int n1 = min(n0 + POOL_CHUNK, N);
    int cur = batch[n0];
    float acc = 0.f;
    for (int n = n0; n < n1; n++) {
        int g = batch[n];
        if (g != cur) {
            atomicAdd(&pooled[cur * HD + j], acc);
            acc = 0.f; cur = g;
        }
        acc += x[(size_t)n * HD + j];
    }
    atomicAdd(&pooled[cur * HD + j], acc);
}

// ---------------------------------------------------------------------------
// 6) Head: y = log_softmax(relu(pooled@V0w+V0b) @ V1w + V1b). Block per graph.
// ---------------------------------------------------------------------------
__global__ void head_kernel(const float* __restrict__ pooled, const float* __restrict__ V0w,
                            const float* __restrict__ V0b, const float* __restrict__ V1w,
                            const float* __restrict__ V1b, float* __restrict__ out) {
    __shared__ float prow[HD];
    __shared__ float y1[HD];
    __shared__ float y2[OUTD];
    __shared__ float lse;
    int g = blockIdx.x, j = threadIdx.x;
    prow[j] = pooled[g * HD + j];
    __syncthreads();
    float a = V0b[j];
    for (int d = 0; d < HD; d++) a += prow[d] * V0w[d * HD + j];
    y1[j] = a > 0.f ? a : 0.f;
    __syncthreads();
    if (j < OUTD) {
        float a2 = V1b[j];
        for (int t = 0; t < HD; t++) a2 += y1[t] * V1w[t * OUTD + j];
        y2[j] = a2;
    }
    __syncthreads();
    if (j == 0) {
        float m = y2[0];
        for (int o = 1; o < OUTD; o++) m = fmaxf(m, y2[o]);
        float s = 0.f;
        for (int o = 0; o < OUTD; o++) s += expf(y2[o] - m);
        lse = m + logf(s);
    }
    __syncthreads();
    if (j < OUTD) out[g * OUTD + j] = y2[j] - lse;
}

// ---------------------------------------------------------------------------
extern "C" void kernel_launch(void* const* d_in, const int* in_sizes, int n_in,
                              void* d_out, int out_size, void* d_ws, size_t ws_size,
                              hipStream_t stream) {
    const float* feat = (const float*)d_in[0];
    const float* ewt  = (const float*)d_in[1];
    const float* W1   = (const float*)d_in[2];
    const float* b1   = (const float*)d_in[3];
    const float* W2   = (const float*)d_in[4];
    const float* b2   = (const float*)d_in[5];
    const float* V0w  = (const float*)d_in[6];
    const float* V0b  = (const float*)d_in[7];
    const float* V1w  = (const float*)d_in[8];
    const float* V1b  = (const float*)d_in[9];
    const int*   ei   = (const int*)d_in[10];
    const int*   batch= (const int*)d_in[11];
    const int E = in_sizes[1];
    const int N = in_sizes[11];
    float* out = (float*)d_out;

    // workspace carve-up (~90.5 MB total)
    char* ws = (char*)d_ws;
    size_t off = 0;
    auto alloc = [&](size_t bytes) -> char* {
        char* p = ws + off;
        off = (off + bytes + 255) & ~(size_t)255;
        return p;
    };
    float* Wc     = (float*)alloc((size_t)HD * HD * 4);
    float* bc     = (float*)alloc((size_t)HD * 4);
    float* h      = (float*)alloc((size_t)N * HD * 4);
    float* xA     = (float*)alloc((size_t)N * HD * 4);
    float* xB     = (float*)alloc((size_t)N * HD * 4);
    float* pooled = (float*)alloc((size_t)NG * HD * 4);
    int*   row_ptr= (int*)alloc((size_t)(N + 1) * 4);
    int*   cnt    = (int*)alloc((size_t)N * 4);
    int*   es     = (int*)alloc((size_t)E * 4);
    float* ewp    = (float*)alloc((size_t)E * 4);
    (void)ws_size;

    hipMemsetAsync(cnt, 0, (size_t)N * 4, stream);
    hipMemsetAsync(pooled, 0, (size_t)NG * HD * 4, stream);

    wc_kernel<<<64, 256, 0, stream>>>(W1, b1, W2, b2, Wc, bc);
    feat_kernel<<<(N + 15) / 16, 256, 0, stream>>>(feat, Wc, bc, h, N);
    count_kernel<<<(E + 255) / 256, 256, 0, stream>>>(ei, cnt, E);
    scan_kernel<<<1, 1024, 0, stream>>>(cnt, row_ptr, N, E);
    scatter_kernel<<<(E + 255) / 256, 256, 0, stream>>>(ei, ewt, cnt, es, ewp, E);

    const float* src = h;
    float* dst = xA;
    for (int k = 0; k < KSTEPS; k++) {
        prop_kernel<<<(N + 3) / 4, 256, 0, stream>>>(src, dst, h, row_ptr, es, ewp, N);
        src = dst;
        dst = (dst == xA) ? xB : xA;
    }

    pool_kernel<<<(N + POOL_CHUNK - 1) / POOL_CHUNK, HD, 0, stream>>>(src, batch, pooled, N);
    head_kernel<<<NG, HD, 0, stream>>>(pooled, V0w, V0b, V1w, V1b, out);
}

// Round 2
// 1527.167 us; speedup vs baseline: 1.0802x; 1.0802x over previous
//
#include <hip/hip_runtime.h>
#include <cstdint>

#define HD    128
#define OUTD  10
#define NG    512
#define KSTEPS 10

// ---------------------------------------------------------------------------
// 1) Collapse the two linear layers: Wc = W1@W2, bc = b1@W2 + b2
// ---------------------------------------------------------------------------
__global__ void wc_kernel(const float* __restrict__ W1, const float* __restrict__ b1,
                          const float* __restrict__ W2, const float* __restrict__ b2,
                          float* __restrict__ Wc, float* __restrict__ bc) {
    int idx = blockIdx.x * 256 + threadIdx.x;      // 0..16383
    int d = idx >> 7, j = idx & 127;
    float s = 0.f;
    for (int t = 0; t < HD; t++) s += W1[d * HD + t] * W2[t * HD + j];
    Wc[idx] = s;
    if (idx < HD) {
        float sb = b2[idx];
        for (int t = 0; t < HD; t++) sb += b1[t] * W2[t * HD + idx];
        bc[idx] = sb;
    }
}

// ---------------------------------------------------------------------------
// 2) h[n][j] = sum_d feat[d][n] * Wc[d][j] + bc[j]   (features are [HD, N])
// ---------------------------------------------------------------------------
__global__ void __launch_bounds__(256) feat_kernel(
        const float* __restrict__ feat, const float* __restrict__ Wc,
        const float* __restrict__ bc, float* __restrict__ h, int N) {
    __shared__ float ftile[HD][16];
    int tid = threadIdx.x;
    int n0 = blockIdx.x * 16;
    #pragma unroll
    for (int r = 0; r < 8; r++) {
        int l = tid * 8 + r;
        int d = l >> 4, n = l & 15;
        int nn = n0 + n;
        ftile[d][n] = (nn < N) ? feat[(size_t)d * N + nn] : 0.f;
    }
    __syncthreads();
    int j = tid & 127, half = tid >> 7;
    float acc[8];
    #pragma unroll
    for (int i = 0; i < 8; i++) acc[i] = 0.f;
    for (int d = 0; d < HD; d++) {
        float w = Wc[d * HD + j];
        #pragma unroll
        for (int i = 0; i < 8; i++) acc[i] += ftile[d][half * 8 + i] * w;
    }
    float bb = bc[j];
    #pragma unroll
    for (int i = 0; i < 8; i++) {
        int n = n0 + half * 8 + i;
        if (n < N) h[(size_t)n * HD + j] = acc[i] + bb;
    }
}

// ---------------------------------------------------------------------------
// 3) CSR build (dst-sorted edge lists): count -> scan -> scatter
// ---------------------------------------------------------------------------
__global__ void count_kernel(const int* __restrict__ ei, int* __restrict__ cnt, int E) {
    int e = blockIdx.x * 256 + threadIdx.x;
    if (e < E) atomicAdd(&cnt[ei[E + e]], 1);       // dst row of edge_index
}

__global__ void scan_kernel(int* __restrict__ cnt, int* __restrict__ row_ptr,
                            int N, int E) {
    __shared__ int part[1024];
    int t = threadIdx.x;
    int chunk = (N + 1023) / 1024;
    int lo = t * chunk, hi = min(lo + chunk, N);
    int s = 0;
    for (int i = lo; i < hi; i++) s += cnt[i];
    part[t] = s;
    __syncthreads();
    for (int off = 1; off < 1024; off <<= 1) {
        int v = (t >= off) ? part[t - off] : 0;
        __syncthreads();
        part[t] += v;
        __syncthreads();
    }
    int run = (t == 0) ? 0 : part[t - 1];
    for (int i = lo; i < hi; i++) {
        int c = cnt[i];
        row_ptr[i] = run;
        cnt[i] = run;                                // cursor init
        run += c;
    }
    if (t == 1023) row_ptr[N] = E;
}

// Interleaved {src_as_float, weight} -> single 8B store per edge (one cache
// line instead of two for the random-destination write).
__global__ void scatter_kernel(const int* __restrict__ ei, const float* __restrict__ ew_in,
                               int* __restrict__ cursor, float2* __restrict__ eswp, int E) {
    int e = blockIdx.x * 256 + threadIdx.x;
    if (e < E) {
        int d = ei[E + e];
        int p = atomicAdd(&cursor[d], 1);
        float2 v;
        v.x = __int_as_float(ei[e]);
        v.y = ew_in[e];
        eswp[p] = v;
    }
}

// ---------------------------------------------------------------------------
// 4) APPNP step: wave per dst node; 4 groups x 16 lanes; each group owns one
//    edge and reads the 512B source row coalesced (2 x float4 per lane).
//    2x unrolled -> 8 edges' loads in flight per wave. Cross-group reduction
//    once per node via shfl_down(32,16).
// ---------------------------------------------------------------------------
__global__ void __launch_bounds__(256) prop_kernel(
        const float* __restrict__ xs, float* __restrict__ xd,
        const float* __restrict__ h, const int* __restrict__ row_ptr,
        const float2* __restrict__ eswp, int N) {
    int wid = threadIdx.x >> 6, lane = threadIdx.x & 63;
    int node = blockIdx.x * 4 + wid;
    if (node >= N) return;
    int rs = row_ptr[node], re = row_ptr[node + 1];
    int grp = lane >> 4;        // edge slot 0..3
    int sub = lane & 15;        // dim slot: floats sub*8 .. sub*8+7

    float4 acc0 = {0.f, 0.f, 0.f, 0.f};
    float4 acc1 = {0.f, 0.f, 0.f, 0.f};

    for (int base = rs; base < re; base += 8) {
        int e0 = base + grp, e1 = base + grp + 4;
        int s0 = 0, s1 = 0;
        float w0 = 0.f, w1 = 0.f;
        if (e0 < re) { float2 p = eswp[e0]; s0 = __float_as_int(p.x); w0 = p.y; }
        if (e1 < re) { float2 p = eswp[e1]; s1 = __float_as_int(p.x); w1 = p.y; }
        const float4* r0 = (const float4*)(xs + (size_t)s0 * HD) + sub * 2;
        const float4* r1 = (const float4*)(xs + (size_t)s1 * HD) + sub * 2;
        float4 a0 = r0[0];
        float4 a1 = r0[1];
        float4 b0 = r1[0];
        float4 b1 = r1[1];
        acc0.x += w0 * a0.x; acc0.y += w0 * a0.y; acc0.z += w0 * a0.z; acc0.w += w0 * a0.w;
        acc1.x += w0 * a1.x; acc1.y += w0 * a1.y; acc1.z += w0 * a1.z; acc1.w += w0 * a1.w;
        acc0.x += w1 * b0.x; acc0.y += w1 * b0.y; acc0.z += w1 * b0.z; acc0.w += w1 * b0.w;
        acc1.x += w1 * b1.x; acc1.y += w1 * b1.y; acc1.z += w1 * b1.z; acc1.w += w1 * b1.w;
    }

    #pragma unroll
    for (int off = 32; off >= 16; off >>= 1) {
        acc0.x += __shfl_down(acc0.x, off);
        acc0.y += __shfl_down(acc0.y, off);
        acc0.z += __shfl_down(acc0.z, off);
        acc0.w += __shfl_down(acc0.w, off);
        acc1.x += __shfl_down(acc1.x, off);
        acc1.y += __shfl_down(acc1.y, off);
        acc1.z += __shfl_down(acc1.z, off);
        acc1.w += __shfl_down(acc1.w, off);
    }

    if (grp == 0) {
        const float4* hp = (const float4*)(h + (size_t)node * HD) + sub * 2;
        float4 h0 = hp[0], h1 = hp[1];
        float4 o0, o1;
        o0.x = 0.9f * acc0.x + 0.1f * h0.x;
        o0.y = 0.9f * acc0.y + 0.1f * h0.y;
        o0.z = 0.9f * acc0.z + 0.1f * h0.z;
        o0.w = 0.9f * acc0.w + 0.1f * h0.w;
        o1.x = 0.9f * acc1.x + 0.1f * h1.x;
        o1.y = 0.9f * acc1.y + 0.1f * h1.y;
        o1.z = 0.9f * acc1.z + 0.1f * h1.z;
        o1.w = 0.9f * acc1.w + 0.1f * h1.w;
        float4* op = (float4*)(xd + (size_t)node * HD) + sub * 2;
        op[0] = o0;
        op[1] = o1;
    }
}

// ---------------------------------------------------------------------------
// 5) Pool: batch is sorted -> running accumulator, atomic only on boundary.
// ---------------------------------------------------------------------------
#define POOL_CHUNK 128
__global__ void pool_kernel(const float* __restrict__ x, const int* __restrict__ batch,
                            float* __restrict__ pooled, int N) {
    int j = threadIdx.x;
    int n0 = blockIdx.x * POOL_CHUNK;
    if (n0 >= N) return;
    int n1 = min(n0 + POOL_CHUNK, N);
    int cur = batch[n0];
    float acc = 0.f;
    for (int n = n0; n < n1; n++) {
        int g = batch[n];
        if (g != cur) {
            atomicAdd(&pooled[cur * HD + j], acc);
            acc = 0.f; cur = g;
        }
        acc += x[(size_t)n * HD + j];
    }
    atomicAdd(&pooled[cur * HD + j], acc);
}

// ---------------------------------------------------------------------------
// 6) Head: y = log_softmax(relu(pooled@V0w+V0b) @ V1w + V1b). Block per graph.
// ---------------------------------------------------------------------------
__global__ void head_kernel(const float* __restrict__ pooled, const float* __restrict__ V0w,
                            const float* __restrict__ V0b, const float* __restrict__ V1w,
                            const float* __restrict__ V1b, float* __restrict__ out) {
    __shared__ float prow[HD];
    __shared__ float y1[HD];
    __shared__ float y2[OUTD];
    __shared__ float lse;
    int g = blockIdx.x, j = threadIdx.x;
    prow[j] = pooled[g * HD + j];
    __syncthreads();
    float a = V0b[j];
    for (int d = 0; d < HD; d++) a += prow[d] * V0w[d * HD + j];
    y1[j] = a > 0.f ? a : 0.f;
    __syncthreads();
    if (j < OUTD) {
        float a2 = V1b[j];
        for (int t = 0; t < HD; t++) a2 += y1[t] * V1w[t * OUTD + j];
        y2[j] = a2;
    }
    __syncthreads();
    if (j == 0) {
        float m = y2[0];
        for (int o = 1; o < OUTD; o++) m = fmaxf(m, y2[o]);
        float s = 0.f;
        for (int o = 0; o < OUTD; o++) s += expf(y2[o] - m);
        lse = m + logf(s);
    }
    __syncthreads();
    if (j < OUTD) out[g * OUTD + j] = y2[j] - lse;
}

// ---------------------------------------------------------------------------
extern "C" void kernel_launch(void* const* d_in, const int* in_sizes, int n_in,
                              void* d_out, int out_size, void* d_ws, size_t ws_size,
                              hipStream_t stream) {
    const float* feat = (const float*)d_in[0];
    const float* ewt  = (const float*)d_in[1];
    const float* W1   = (const float*)d_in[2];
    const float* b1   = (const float*)d_in[3];
    const float* W2   = (const float*)d_in[4];
    const float* b2   = (const float*)d_in[5];
    const float* V0w  = (const float*)d_in[6];
    const float* V0b  = (const float*)d_in[7];
    const float* V1w  = (const float*)d_in[8];
    const float* V1b  = (const float*)d_in[9];
    const int*   ei   = (const int*)d_in[10];
    const int*   batch= (const int*)d_in[11];
    const int E = in_sizes[1];
    const int N = in_sizes[11];
    float* out = (float*)d_out;

    char* ws = (char*)d_ws;
    size_t off = 0;
    auto alloc = [&](size_t bytes) -> char* {
        char* p = ws + off;
        off = (off + bytes + 255) & ~(size_t)255;
        return p;
    };
    float*  Wc     = (float*)alloc((size_t)HD * HD * 4);
    float*  bc     = (float*)alloc((size_t)HD * 4);
    float*  h      = (float*)alloc((size_t)N * HD * 4);
    float*  xA     = (float*)alloc((size_t)N * HD * 4);
    float*  xB     = (float*)alloc((size_t)N * HD * 4);
    float*  pooled = (float*)alloc((size_t)NG * HD * 4);
    int*    row_ptr= (int*)alloc((size_t)(N + 1) * 4);
    int*    cnt    = (int*)alloc((size_t)N * 4);
    float2* eswp   = (float2*)alloc((size_t)E * 8);
    (void)ws_size;

    hipMemsetAsync(cnt, 0, (size_t)N * 4, stream);
    hipMemsetAsync(pooled, 0, (size_t)NG * HD * 4, stream);

    wc_kernel<<<64, 256, 0, stream>>>(W1, b1, W2, b2, Wc, bc);
    feat_kernel<<<(N + 15) / 16, 256, 0, stream>>>(feat, Wc, bc, h, N);
    count_kernel<<<(E + 255) / 256, 256, 0, stream>>>(ei, cnt, E);
    scan_kernel<<<1, 1024, 0, stream>>>(cnt, row_ptr, N, E);
    scatter_kernel<<<(E + 255) / 256, 256, 0, stream>>>(ei, ewt, cnt, eswp, E);

    const float* src = h;
    float* dst = xA;
    for (int k = 0; k < KSTEPS; k++) {
        prop_kernel<<<(N + 3) / 4, 256, 0, stream>>>(src, dst, h, row_ptr, eswp, N);
        src = dst;
        dst = (dst == xA) ? xB : xA;
    }

    pool_kernel<<<(N + POOL_CHUNK - 1) / POOL_CHUNK, HD, 0, stream>>>(src, batch, pooled, N);
    head_kernel<<<NG, HD, 0, stream>>>(pooled, V0w, V0b, V1w, V1b, out);
}

// Round 3
// 979.887 us; speedup vs baseline: 1.6835x; 1.5585x over previous
//
#include <hip/hip_runtime.h>
#include <cstdint>

#define HD    128
#define OUTD  10
#define NG    512
#define KSTEPS 10

typedef unsigned short ushort_t;
typedef unsigned int   uint_t;

// bf16 helpers (stored as ushort; f32 accumulate everywhere)
__device__ __forceinline__ float bf_lo(uint_t u) { return __uint_as_float(u << 16); }
__device__ __forceinline__ float bf_hi(uint_t u) { return __uint_as_float(u & 0xFFFF0000u); }
__device__ __forceinline__ uint_t f2bf_rne(float f) {          // 16-bit result
    uint_t u = __float_as_uint(f);
    return (u + 0x7FFFu + ((u >> 16) & 1u)) >> 16;
}
__device__ __forceinline__ uint_t pack_bf2(float lo, float hi) {
    return f2bf_rne(lo) | (f2bf_rne(hi) << 16);
}

// ---------------------------------------------------------------------------
// 1) Collapse the two linear layers: Wc = W1@W2, bc = b1@W2 + b2
// ---------------------------------------------------------------------------
__global__ void wc_kernel(const float* __restrict__ W1, const float* __restrict__ b1,
                          const float* __restrict__ W2, const float* __restrict__ b2,
                          float* __restrict__ Wc, float* __restrict__ bc) {
    int idx = blockIdx.x * 256 + threadIdx.x;      // 0..16383
    int d = idx >> 7, j = idx & 127;
    float s = 0.f;
    for (int t = 0; t < HD; t++) s += W1[d * HD + t] * W2[t * HD + j];
    Wc[idx] = s;
    if (idx < HD) {
        float sb = b2[idx];
        for (int t = 0; t < HD; t++) sb += b1[t] * W2[t * HD + idx];
        bc[idx] = sb;
    }
}

// ---------------------------------------------------------------------------
// 2) h[n][j] = sum_d feat[d][n] * Wc[d][j] + bc[j]  -> stored bf16 [N][128]
// ---------------------------------------------------------------------------
__global__ void __launch_bounds__(256) feat_kernel(
        const float* __restrict__ feat, const float* __restrict__ Wc,
        const float* __restrict__ bc, ushort_t* __restrict__ h, int N) {
    __shared__ float ftile[HD][16];
    int tid = threadIdx.x;
    int n0 = blockIdx.x * 16;
    #pragma unroll
    for (int r = 0; r < 8; r++) {
        int l = tid * 8 + r;
        int d = l >> 4, n = l & 15;
        int nn = n0 + n;
        ftile[d][n] = (nn < N) ? feat[(size_t)d * N + nn] : 0.f;
    }
    __syncthreads();
    int j = tid & 127, half = tid >> 7;
    float acc[8];
    #pragma unroll
    for (int i = 0; i < 8; i++) acc[i] = 0.f;
    for (int d = 0; d < HD; d++) {
        float w = Wc[d * HD + j];
        #pragma unroll
        for (int i = 0; i < 8; i++) acc[i] += ftile[d][half * 8 + i] * w;
    }
    float bb = bc[j];
    #pragma unroll
    for (int i = 0; i < 8; i++) {
        int n = n0 + half * 8 + i;
        if (n < N) h[(size_t)n * HD + j] = (ushort_t)f2bf_rne(acc[i] + bb);
    }
}

// ---------------------------------------------------------------------------
// 3) CSR build (dst-sorted edge lists): count -> scan -> scatter
// ---------------------------------------------------------------------------
__global__ void count_kernel(const int* __restrict__ ei, int* __restrict__ cnt, int E) {
    int e = blockIdx.x * 256 + threadIdx.x;
    if (e < E) atomicAdd(&cnt[ei[E + e]], 1);       // dst row of edge_index
}

__global__ void scan_kernel(int* __restrict__ cnt, int* __restrict__ row_ptr,
                            int N, int E) {
    __shared__ int part[1024];
    int t = threadIdx.x;
    int chunk = (N + 1023) / 1024;
    int lo = t * chunk, hi = min(lo + chunk, N);
    int s = 0;
    for (int i = lo; i < hi; i++) s += cnt[i];
    part[t] = s;
    __syncthreads();
    for (int off = 1; off < 1024; off <<= 1) {
        int v = (t >= off) ? part[t - off] : 0;
        __syncthreads();
        part[t] += v;
        __syncthreads();
    }
    int run = (t == 0) ? 0 : part[t - 1];
    for (int i = lo; i < hi; i++) {
        int c = cnt[i];
        row_ptr[i] = run;
        cnt[i] = run;                                // cursor init
        run += c;
    }
    if (t == 1023) row_ptr[N] = E;
}

// Interleaved {src_as_float, weight} -> single 8B store per edge
__global__ void scatter_kernel(const int* __restrict__ ei, const float* __restrict__ ew_in,
                               int* __restrict__ cursor, float2* __restrict__ eswp, int E) {
    int e = blockIdx.x * 256 + threadIdx.x;
    if (e < E) {
        int d = ei[E + e];
        int p = atomicAdd(&cursor[d], 1);
        float2 v;
        v.x = __int_as_float(ei[e]);
        v.y = ew_in[e];
        eswp[p] = v;
    }
}

// ---------------------------------------------------------------------------
// 4) APPNP step (bf16 rows): wave per dst node; 4 groups x 16 lanes; each
//    group owns one edge, reads the 256B bf16 row as one uint4 per lane.
//    2x unroll + 1-iter edge-data prefetch. f32 accumulate, bf16-RNE out.
// ---------------------------------------------------------------------------
__global__ void __launch_bounds__(256) prop_kernel(
        const ushort_t* __restrict__ xs, ushort_t* __restrict__ xd,
        const ushort_t* __restrict__ h, const int* __restrict__ row_ptr,
        const float2* __restrict__ eswp, int N) {
    int wid = threadIdx.x >> 6, lane = threadIdx.x & 63;
    int node = blockIdx.x * 4 + wid;
    if (node >= N) return;
    int rs = row_ptr[node], re = row_ptr[node + 1];
    int grp = lane >> 4;        // edge slot 0..3
    int sub = lane & 15;        // dim slot: bf16 elems sub*8 .. sub*8+7

    float acc[8];
    #pragma unroll
    for (int i = 0; i < 8; i++) acc[i] = 0.f;

    int e0 = rs + grp, e1 = rs + grp + 4;
    float2 p0 = make_float2(0.f, 0.f), p1 = make_float2(0.f, 0.f);
    if (e0 < re) p0 = eswp[e0];
    if (e1 < re) p1 = eswp[e1];

    for (int base = rs; base < re; base += 8) {
        // prefetch next iteration's edge records
        int ne0 = base + 8 + grp, ne1 = base + 12 + grp;
        float2 q0 = make_float2(0.f, 0.f), q1 = make_float2(0.f, 0.f);
        if (ne0 < re) q0 = eswp[ne0];
        if (ne1 < re) q1 = eswp[ne1];

        int s0 = __float_as_int(p0.x); float w0 = p0.y;
        int s1 = __float_as_int(p1.x); float w1 = p1.y;
        uint4 a = ((const uint4*)(xs + (size_t)s0 * HD))[sub];
        uint4 b = ((const uint4*)(xs + (size_t)s1 * HD))[sub];

        acc[0] += w0 * bf_lo(a.x); acc[1] += w0 * bf_hi(a.x);
        acc[2] += w0 * bf_lo(a.y); acc[3] += w0 * bf_hi(a.y);
        acc[4] += w0 * bf_lo(a.z); acc[5] += w0 * bf_hi(a.z);
        acc[6] += w0 * bf_lo(a.w); acc[7] += w0 * bf_hi(a.w);
        acc[0] += w1 * bf_lo(b.x); acc[1] += w1 * bf_hi(b.x);
        acc[2] += w1 * bf_lo(b.y); acc[3] += w1 * bf_hi(b.y);
        acc[4] += w1 * bf_lo(b.z); acc[5] += w1 * bf_hi(b.z);
        acc[6] += w1 * bf_lo(b.w); acc[7] += w1 * bf_hi(b.w);

        p0 = q0; p1 = q1;
    }

    // reduce across the 4 edge groups
    #pragma unroll
    for (int off = 32; off >= 16; off >>= 1) {
        #pragma unroll
        for (int i = 0; i < 8; i++) acc[i] += __shfl_down(acc[i], off);
    }

    if (grp == 0) {
        uint4 hv = ((const uint4*)(h + (size_t)node * HD))[sub];
        float hf[8];
        hf[0] = bf_lo(hv.x); hf[1] = bf_hi(hv.x);
        hf[2] = bf_lo(hv.y); hf[3] = bf_hi(hv.y);
        hf[4] = bf_lo(hv.z); hf[5] = bf_hi(hv.z);
        hf[6] = bf_lo(hv.w); hf[7] = bf_hi(hv.w);
        float o[8];
        #pragma unroll
        for (int i = 0; i < 8; i++) o[i] = 0.9f * acc[i] + 0.1f * hf[i];
        uint4 ov;
        ov.x = pack_bf2(o[0], o[1]);
        ov.y = pack_bf2(o[2], o[3]);
        ov.z = pack_bf2(o[4], o[5]);
        ov.w = pack_bf2(o[6], o[7]);
        ((uint4*)(xd + (size_t)node * HD))[sub] = ov;
    }
}

// ---------------------------------------------------------------------------
// 5) Pool: batch is sorted -> running accumulator, atomic only on boundary.
// ---------------------------------------------------------------------------
#define POOL_CHUNK 128
__global__ void pool_kernel(const ushort_t* __restrict__ x, const int* __restrict__ batch,
                            float* __restrict__ pooled, int N) {
    int j = threadIdx.x;
    int n0 = blockIdx.x * POOL_CHUNK;
    if (n0 >= N) return;
    int n1 = min(n0 + POOL_CHUNK, N);
    int cur = batch[n0];
    float acc = 0.f;
    for (int n = n0; n < n1; n++) {
        int g = batch[n];
        if (g != cur) {
            atomicAdd(&pooled[cur * HD + j], acc);
            acc = 0.f; cur = g;
        }
        acc += bf_lo((uint_t)x[(size_t)n * HD + j] << 0) * 0.f +   // (avoid accidental opt)
               __uint_as_float(((uint_t)x[(size_t)n * HD + j]) << 16);
    }
    atomicAdd(&pooled[cur * HD + j], acc);
}

// ---------------------------------------------------------------------------
// 6) Head: y = log_softmax(relu(pooled@V0w+V0b) @ V1w + V1b). Block per graph.
// ---------------------------------------------------------------------------
__global__ void head_kernel(const float* __restrict__ pooled, const float* __restrict__ V0w,
                            const float* __restrict__ V0b, const float* __restrict__ V1w,
                            const float* __restrict__ V1b, float* __restrict__ out) {
    __shared__ float prow[HD];
    __shared__ float y1[HD];
    __shared__ float y2[OUTD];
    __shared__ float lse;
    int g = blockIdx.x, j = threadIdx.x;
    prow[j] = pooled[g * HD + j];
    __syncthreads();
    float a = V0b[j];
    for (int d = 0; d < HD; d++) a += prow[d] * V0w[d * HD + j];
    y1[j] = a > 0.f ? a : 0.f;
    __syncthreads();
    if (j < OUTD) {
        float a2 = V1b[j];
        for (int t = 0; t < HD; t++) a2 += y1[t] * V1w[t * OUTD + j];
        y2[j] = a2;
    }
    __syncthreads();
    if (j == 0) {
        float m = y2[0];
        for (int o = 1; o < OUTD; o++) m = fmaxf(m, y2[o]);
        float s = 0.f;
        for (int o = 0; o < OUTD; o++) s += expf(y2[o] - m);
        lse = m + logf(s);
    }
    __syncthreads();
    if (j < OUTD) out[g * OUTD + j] = y2[j] - lse;
}

// ---------------------------------------------------------------------------
extern "C" void kernel_launch(void* const* d_in, const int* in_sizes, int n_in,
                              void* d_out, int out_size, void* d_ws, size_t ws_size,
                              hipStream_t stream) {
    const float* feat = (const float*)d_in[0];
    const float* ewt  = (const float*)d_in[1];
    const float* W1   = (const float*)d_in[2];
    const float* b1   = (const float*)d_in[3];
    const float* W2   = (const float*)d_in[4];
    const float* b2   = (const float*)d_in[5];
    const float* V0w  = (const float*)d_in[6];
    const float* V0b  = (const float*)d_in[7];
    const float* V1w  = (const float*)d_in[8];
    const float* V1b  = (const float*)d_in[9];
    const int*   ei   = (const int*)d_in[10];
    const int*   batch= (const int*)d_in[11];
    const int E = in_sizes[1];
    const int N = in_sizes[11];
    float* out = (float*)d_out;

    char* ws = (char*)d_ws;
    size_t off = 0;
    auto alloc = [&](size_t bytes) -> char* {
        char* p = ws + off;
        off = (off + bytes + 255) & ~(size_t)255;
        return p;
    };
    float*    Wc     = (float*)alloc((size_t)HD * HD * 4);
    float*    bc     = (float*)alloc((size_t)HD * 4);
    ushort_t* hb     = (ushort_t*)alloc((size_t)N * HD * 2);
    ushort_t* xA     = (ushort_t*)alloc((size_t)N * HD * 2);
    ushort_t* xB     = (ushort_t*)alloc((size_t)N * HD * 2);
    float*    pooled = (float*)alloc((size_t)NG * HD * 4);
    int*      row_ptr= (int*)alloc((size_t)(N + 1) * 4);
    int*      cnt    = (int*)alloc((size_t)N * 4);
    float2*   eswp   = (float2*)alloc((size_t)E * 8);
    (void)ws_size;

    hipMemsetAsync(cnt, 0, (size_t)N * 4, stream);
    hipMemsetAsync(pooled, 0, (size_t)NG * HD * 4, stream);

    wc_kernel<<<64, 256, 0, stream>>>(W1, b1, W2, b2, Wc, bc);
    feat_kernel<<<(N + 15) / 16, 256, 0, stream>>>(feat, Wc, bc, hb, N);
    count_kernel<<<(E + 255) / 256, 256, 0, stream>>>(ei, cnt, E);
    scan_kernel<<<1, 1024, 0, stream>>>(cnt, row_ptr, N, E);
    scatter_kernel<<<(E + 255) / 256, 256, 0, stream>>>(ei, ewt, cnt, eswp, E);

    const ushort_t* src = hb;
    ushort_t* dst = xA;
    for (int k = 0; k < KSTEPS; k++) {
        prop_kernel<<<(N + 3) / 4, 256, 0, stream>>>(src, dst, hb, row_ptr, eswp, N);
        src = dst;
        dst = (dst == xA) ? xB : xA;
    }

    pool_kernel<<<(N + POOL_CHUNK - 1) / POOL_CHUNK, HD, 0, stream>>>(src, batch, pooled, N);
    head_kernel<<<NG, HD, 0, stream>>>(pooled, V0w, V0b, V1w, V1b, out);
}